// Round 11
// baseline (490.612 us; speedup 1.0000x reference)
//
#include <hip/hip_runtime.h>
#include <stdint.h>

#define S_LEN 2048
#define NHEAD 16
#define DHEAD 64
#define DMODEL 1024
#define MROWS 8192  // B*S

typedef unsigned short ushort_t;
typedef __attribute__((ext_vector_type(8))) __bf16 bf16x8;
typedef __attribute__((ext_vector_type(4))) float f32x4;

__device__ __forceinline__ float bf2f(ushort_t h) {
    union { unsigned int u; float f; } v; v.u = ((unsigned int)h) << 16; return v.f;
}
__device__ __forceinline__ ushort_t f2bf(float f) {
    union { float f; unsigned int u; } v; v.f = f;
    unsigned int u = v.u + 0x7fffu + ((v.u >> 16) & 1u);  // round-to-nearest-even
    return (ushort_t)(u >> 16);
}

// Direct global->LDS 16B async copy. LDS dest is wave-uniform base + lane*16.
__device__ __forceinline__ void gload_lds16(const void* g, void* l)
{
    auto* g1 = reinterpret_cast<const __attribute__((address_space(1))) void*>(
        reinterpret_cast<uintptr_t>(g));
    auto* l3 = reinterpret_cast<__attribute__((address_space(3))) void*>(
        reinterpret_cast<uintptr_t>(l));
    __builtin_amdgcn_global_load_lds(g1, l3, 16, 0, 0);
}

// ---------------------------------------------------------------------------
// Dtype detection, both tensors in one dispatch.
// ---------------------------------------------------------------------------
__global__ void detect_dtype2(const unsigned int* __restrict__ q,
                              const unsigned int* __restrict__ w,
                              int* __restrict__ flag)
{
    __shared__ int cnt;
    if (threadIdx.x == 0) cnt = 0;
    __syncthreads();
    const unsigned int* src = blockIdx.x ? w : q;
    int c = 0;
    for (int i = 0; i < 8; ++i) {
        const unsigned int word = src[threadIdx.x * 8 + i];   // first 512 words
        const unsigned int lo = word & 0xffffu;
        const unsigned int e = (lo >> 7) & 0xffu;        // bf16 exponent field
        if (lo == 0u || (e >= 96u && e <= 160u)) ++c;    // "sane" bf16
    }
    atomicAdd(&cnt, c);
    __syncthreads();
    if (threadIdx.x == 0) flag[blockIdx.x] = (cnt < 400) ? 1 : 0;
}

// ---------------------------------------------------------------------------
// mask -> per 128x128 tile flag (1 = all nonzero -> skip elementwise path)
// ---------------------------------------------------------------------------
__global__ void mask_flags(const int* __restrict__ mask, int* __restrict__ flags)
{
    __shared__ int ok_s;
    if (threadIdx.x == 0) ok_s = 1;
    __syncthreads();
    const int t = blockIdx.x;            // 0..255
    const int tq = t >> 4, tk = t & 15;
    int ok = 1;
    for (int i = 0; i < 64; ++i) {
        const int idx = i * 256 + threadIdx.x;    // 0..16383
        const int r = idx >> 7, c = idx & 127;
        if (mask[(size_t)(tq * 128 + r) * S_LEN + tk * 128 + c] == 0) { ok = 0; break; }
    }
    if (!ok) atomicAnd(&ok_s, 0);
    __syncthreads();
    if (threadIdx.x == 0) flags[t] = ok_s;
}

__device__ __forceinline__ float loadscal(const void* b, int i, bool f32)
{
    return f32 ? ((const float*)b)[i] : bf2f(((const ushort_t*)b)[i]);
}

// ---------------------------------------------------------------------------
// One-shot dtype normalization: src (f32 or bf16, per flag) -> bf16.
// ---------------------------------------------------------------------------
__device__ __forceinline__ void conv_body(const void* __restrict__ src,
                                          ushort_t* __restrict__ dst,
                                          int n8, bool f32)
{
    const int stride = gridDim.x * 256;
    for (int i = blockIdx.x * 256 + threadIdx.x; i < n8; i += stride) {
        if (f32) {
            const float4 a = ((const float4*)src)[2 * (size_t)i];
            const float4 b = ((const float4*)src)[2 * (size_t)i + 1];
            union { ushort_t u[8]; uint4 v; } p;
            p.u[0] = f2bf(a.x); p.u[1] = f2bf(a.y); p.u[2] = f2bf(a.z); p.u[3] = f2bf(a.w);
            p.u[4] = f2bf(b.x); p.u[5] = f2bf(b.y); p.u[6] = f2bf(b.z); p.u[7] = f2bf(b.w);
            ((uint4*)dst)[i] = p.v;
        } else {
            ((uint4*)dst)[i] = ((const uint4*)src)[i];
        }
    }
}

__global__ __launch_bounds__(256)
void conv_bf16(const void* __restrict__ src, ushort_t* __restrict__ dst,
               int n8, const int* __restrict__ dflag, int fidx)
{
    conv_body(src, dst, n8, dflag[fidx] != 0);
}

// Five-slice upfront conversion: z=0..2 weights (dflag[1]), z=3..4
// activations (dflag[0]).
__global__ __launch_bounds__(256)
void conv_qkvw(const void* __restrict__ wq, ushort_t* __restrict__ dwq,
               const void* __restrict__ wk, ushort_t* __restrict__ dwk,
               const void* __restrict__ wv, ushort_t* __restrict__ dwv,
               const void* __restrict__ aq, ushort_t* __restrict__ daq,
               const void* __restrict__ ak, ushort_t* __restrict__ dak,
               int wn8, int an8, const int* __restrict__ dflag)
{
    const int z = blockIdx.z;
    const void* src;
    ushort_t* dst;
    int n8;
    bool f32;
    if (z < 3) {
        n8 = wn8; f32 = dflag[1] != 0;
        src = (z == 0) ? wq : (z == 1) ? wk : wv;
        dst = (z == 0) ? dwq : (z == 1) ? dwk : dwv;
    } else {
        n8 = an8; f32 = dflag[0] != 0;
        src = (z == 3) ? aq : ak;
        dst = (z == 3) ? daq : dak;
    }
    conv_body(src, dst, n8, f32);
}

// ---------------------------------------------------------------------------
// 128x64-tile bf16 GEMM (ROUND-11): occupancy experiment. The 128^2 kernel's
// grid (512 blocks) caps the chip at 2 blocks/CU = 2 waves/SIMD, and its
// measured ~13% MFMA util with non-saturated L2 BW points at exposed latency.
// This kernel: grid (64,16) = 1024 blocks = 4 blocks/CU = 4 waves/SIMD (2x
// TLP). 4 waves (2M x 2N, wave-tile 64x32, acc[4][2] = 32 VGPR), LDS
// 3 x (A 8KB + B 4KB) = 36KB (4 blocks = 144KB <= 160KB). Same proven
// 3-buffer counted-vmcnt skeleton; 3 loads/stage -> vmcnt(3).
// ---------------------------------------------------------------------------
__global__ __launch_bounds__(256, 4)
void gemm_n64(const ushort_t* __restrict__ A, const ushort_t* __restrict__ W,
              const void* __restrict__ bias, void* __restrict__ out,
              const int* __restrict__ dflag, int outf)
{
    constexpr int K = DMODEL, N = DMODEL;
    __shared__ ushort_t As[3][128 * 32];   // 8 KB each
    __shared__ ushort_t Bs[3][64 * 32];    // 4 KB each
    const bool bf32 = dflag[1] != 0;
    const bool of   = outf != 0;
    const int tid = threadIdx.x;
    const int lane = tid & 63;
    const int wave = tid >> 6;
    const int lrow = lane & 15, lq = lane >> 4;
    const int m0 = blockIdx.x * 128;
    const int n0 = blockIdx.y * 64;
    const int wr = (wave >> 1) * 64;       // 2 M-waves
    const int wc = (wave & 1) * 32;        // 2 N-waves

    const f32x4 zero4 = {0.f, 0.f, 0.f, 0.f};
    f32x4 acc[4][2];
#pragma unroll
    for (int i = 0; i < 4; ++i)
#pragma unroll
        for (int j = 0; j < 2; ++j) acc[i][j] = zero4;

    // chunk c -> row c>>2, cols (c&3)*8; LDS linear => dest = chunk*16B.
    const int r0  = tid >> 2;              // 0..63
    const int cc0 = (tid & 3) * 8;
    const int lb  = wave * 64 * 8;         // wave-uniform lane-0 chunk
    const int lb1 = (wave * 64 + 256) * 8;

    auto stage = [&](int buf, int k0) __attribute__((always_inline)) {
        gload_lds16(&A[(size_t)(m0 + r0) * K + k0 + cc0],      &As[buf][lb]);
        gload_lds16(&A[(size_t)(m0 + r0 + 64) * K + k0 + cc0], &As[buf][lb1]);
        gload_lds16(&W[(size_t)(n0 + r0) * K + k0 + cc0],      &Bs[buf][lb]);
    };
    auto compute = [&](int buf) __attribute__((always_inline)) {
        bf16x8 af[4], bfr[2];
#pragma unroll
        for (int t = 0; t < 4; ++t)
            af[t] = *(const bf16x8*)(&As[buf][(wr + t * 16 + lrow) * 32 + lq * 8]);
#pragma unroll
        for (int n = 0; n < 2; ++n)
            bfr[n] = *(const bf16x8*)(&Bs[buf][(wc + n * 16 + lrow) * 32 + lq * 8]);
        __builtin_amdgcn_s_setprio(1);
#pragma unroll
        for (int mt = 0; mt < 4; ++mt)
#pragma unroll
            for (int nt = 0; nt < 2; ++nt)
                acc[mt][nt] = __builtin_amdgcn_mfma_f32_16x16x32_bf16(
                    af[mt], bfr[nt], acc[mt][nt], 0, 0, 0);
        __builtin_amdgcn_s_setprio(0);
    };

    // Prologue: tiles 0 and 1 in flight (3 loads each); wait tile0 only.
    stage(0, 0);
    stage(1, 32);
    asm volatile("s_waitcnt vmcnt(3)" ::: "memory");
    __builtin_amdgcn_s_barrier();

#pragma unroll 1
    for (int tt = 0; tt < 32; ++tt) {
        if (tt < 30) stage((tt + 2) % 3, (tt + 2) * 32);   // keep 2 tiles in flight
        compute(tt % 3);
        if (tt < 31) {
            if (tt < 30) asm volatile("s_waitcnt vmcnt(3)" ::: "memory");
            else         asm volatile("s_waitcnt vmcnt(0)" ::: "memory");
            __builtin_amdgcn_s_barrier();
        }
    }

#pragma unroll
    for (int nt = 0; nt < 2; ++nt) {
        const int n = n0 + wc + nt * 16 + lrow;
        const float bv = loadscal(bias, n, bf32);
#pragma unroll
        for (int mt = 0; mt < 4; ++mt) {
            const int mbase = m0 + wr + mt * 16 + lq * 4;
#pragma unroll
            for (int r = 0; r < 4; ++r) {
                const float v = acc[mt][nt][r] + bv;
                const size_t o = (size_t)(mbase + r) * N + n;
                if (of) ((float*)out)[o] = v;
                else    ((ushort_t*)out)[o] = f2bf(v);
            }
        }
    }
}

// ---------------------------------------------------------------------------
// 256x256-tile bf16 GEMM (QK; 3-buffer counted-vmcnt, twice verified).
// Grid (32,4,2) = 256 blocks = 1 block/CU.
// ---------------------------------------------------------------------------
__device__ __forceinline__ void gemm256_core(
    const ushort_t* __restrict__ A, const ushort_t* __restrict__ W,
    const void* __restrict__ bias, void* __restrict__ out,
    bool bf32, bool outf, float scale,
    ushort_t (&As)[3][256 * 32], ushort_t (&Bs)[3][256 * 32])
{
    constexpr int K = DMODEL, N = DMODEL;
    const int tid = threadIdx.x;             // 0..511
    const int lane = tid & 63;
    const int wave = tid >> 6;               // 0..7
    const int lrow = lane & 15, lq = lane >> 4;
    const int Rw = (wave >> 2) * 128;        // wave row base (2 M-waves)
    const int Cw = (wave & 3) * 64;          // wave col base (4 N-waves)
    const int m0 = blockIdx.x * 256;
    const int n0 = blockIdx.y * 256;

    const f32x4 zero4 = {0.f, 0.f, 0.f, 0.f};
    f32x4 acc[8][4];
#pragma unroll
    for (int i = 0; i < 8; ++i)
#pragma unroll
        for (int j = 0; j < 4; ++j) acc[i][j] = zero4;

    const int rowA = tid >> 2;                         // 0..127
    const int sl   = (((tid & 3) ^ (rowA & 3))) * 8;   // swizzled elem offset
    const int lb0  = (wave * 64) * 8;                  // wave-uniform LDS dest
    const int lb1  = (512 + wave * 64) * 8;

    auto stage = [&](int buf, int k0) __attribute__((always_inline)) {
        gload_lds16(&A[(size_t)(m0 + rowA) * K + k0 + sl],       &As[buf][lb0]);
        gload_lds16(&A[(size_t)(m0 + rowA + 128) * K + k0 + sl], &As[buf][lb1]);
        gload_lds16(&W[(size_t)(n0 + rowA) * K + k0 + sl],       &Bs[buf][lb0]);
        gload_lds16(&W[(size_t)(n0 + rowA + 128) * K + k0 + sl], &Bs[buf][lb1]);
    };

    const int lqs8 = (lq ^ (lrow & 3)) * 8;

    auto compute = [&](int buf) __attribute__((always_inline)) {
        const ushort_t* Ad = As[buf];
        const ushort_t* Bd = Bs[buf];
        bf16x8 bfr[4], af[4];
#pragma unroll
        for (int ni = 0; ni < 4; ++ni)
            bfr[ni] = *(const bf16x8*)(&Bd[(Cw + ni * 16 + lrow) * 32 + lqs8]);
#pragma unroll
        for (int mi = 0; mi < 4; ++mi)
            af[mi] = *(const bf16x8*)(&Ad[(Rw + mi * 16 + lrow) * 32 + lqs8]);
        __builtin_amdgcn_s_setprio(1);
#pragma unroll
        for (int mi = 0; mi < 4; ++mi)
#pragma unroll
            for (int ni = 0; ni < 4; ++ni)
                acc[mi][ni] = __builtin_amdgcn_mfma_f32_16x16x32_bf16(
                    af[mi], bfr[ni], acc[mi][ni], 0, 0, 0);
        __builtin_amdgcn_s_setprio(0);
#pragma unroll
        for (int mi = 0; mi < 4; ++mi)
            af[mi] = *(const bf16x8*)(&Ad[(Rw + 64 + mi * 16 + lrow) * 32 + lqs8]);
        __builtin_amdgcn_s_setprio(1);
#pragma unroll
        for (int mi = 0; mi < 4; ++mi)
#pragma unroll
            for (int ni = 0; ni < 4; ++ni)
                acc[4 + mi][ni] = __builtin_amdgcn_mfma_f32_16x16x32_bf16(
                    af[mi], bfr[ni], acc[4 + mi][ni], 0, 0, 0);
        __builtin_amdgcn_s_setprio(0);
    };

    stage(0, 0);
    stage(1, 32);
    asm volatile("s_waitcnt vmcnt(4)" ::: "memory");
    __builtin_amdgcn_s_barrier();

#pragma unroll 1
    for (int tt = 0; tt < 32; ++tt) {
        if (tt < 30) stage((tt + 2) % 3, (tt + 2) * 32);
        compute(tt % 3);
        if (tt < 31) {
            if (tt < 30) asm volatile("s_waitcnt vmcnt(4)" ::: "memory");
            else         asm volatile("s_waitcnt vmcnt(0)" ::: "memory");
            __builtin_amdgcn_s_barrier();
        }
    }

#pragma unroll
    for (int ni = 0; ni < 4; ++ni) {
        const int n = n0 + Cw + ni * 16 + lrow;
        const float bv = loadscal(bias, n, bf32);
#pragma unroll
        for (int mi = 0; mi < 8; ++mi) {
            const int mbase = m0 + Rw + (mi >> 2) * 64 + (mi & 3) * 16 + lq * 4;
#pragma unroll
            for (int r = 0; r < 4; ++r) {
                const float v = (acc[mi][ni][r] + bv) * scale;
                const size_t o = (size_t)(mbase + r) * N + n;
                if (outf) ((float*)out)[o] = v;
                else      ((ushort_t*)out)[o] = f2bf(v);
            }
        }
    }
}

// Batched Q/K projection: z=0 -> Q with epilogue scale 0.125; z=1 -> K.
__global__ __launch_bounds__(512, 2)
void gemm256_qk(const ushort_t* __restrict__ A0, const ushort_t* __restrict__ W0,
                const void* __restrict__ b0, void* __restrict__ o0,
                const ushort_t* __restrict__ A1, const ushort_t* __restrict__ W1,
                const void* __restrict__ b1, void* __restrict__ o1,
                const int* __restrict__ dflag)
{
    __shared__ ushort_t As[3][256 * 32];   // 48 KB
    __shared__ ushort_t Bs[3][256 * 32];   // 48 KB
    const bool z = blockIdx.z != 0;
    gemm256_core(z ? A1 : A0, z ? W1 : W0, z ? b1 : b0, z ? o1 : o0,
                 dflag[1] != 0, false, z ? 1.0f : 0.125f, As, Bs);
}

// ---------------------------------------------------------------------------
// MFMA flash attention — FROZEN inner kernel; grid (x=bh, y=q0t) for XCD L2
// locality (round-10 verified: FETCH 139MB -> 39MB, dur 197 -> 192).
// Q arrives pre-scaled by 0.125 from the Q projection.
// ---------------------------------------------------------------------------
__global__ __launch_bounds__(256, 2)
void attn_mfma(const ushort_t* __restrict__ Q, const ushort_t* __restrict__ K,
               const ushort_t* __restrict__ V, const int* __restrict__ mask,
               const int* __restrict__ flags, ushort_t* __restrict__ X)
{
    constexpr int KP = 72;    // K tile row stride
    constexpr int VP = 130;   // V^T tile row stride (even; bank-spread)
    constexpr int PP = 72;    // P tile row stride
    __shared__ ushort_t Ks[128 * KP];       // 18.0 KB
    __shared__ ushort_t VTs[64 * VP];       // 16.3 KB
    __shared__ ushort_t Ps[4][32 * PP];     // 18.0 KB (per-wave)

    const int tid = threadIdx.x;
    const int lane = tid & 63;
    const int wave = tid >> 6;
    const int lrow = lane & 15, lq = lane >> 4;
    const int bh = blockIdx.x, b = bh >> 4, h = bh & 15;
    const int qt = blockIdx.y;
    const int q0 = qt * 128;
    const int qw = q0 + wave * 32;
    const int coff = h * 64;
    const size_t rowb = (size_t)b * S_LEN;

    // Q fragments (A-operand: m=lrow, k-chunk=lq*8) live in registers
    bf16x8 qf[2][2];
#pragma unroll
    for (int mt = 0; mt < 2; ++mt)
#pragma unroll
        for (int ks = 0; ks < 2; ++ks)
            qf[mt][ks] = *(const bf16x8*)(
                &Q[(rowb + qw + mt * 16 + lrow) * DMODEL + coff + ks * 32 + lq * 8]);

    const f32x4 zero4 = {0.f, 0.f, 0.f, 0.f};
    f32x4 o[2][4];
    float mr[2][4], lr[2][4];
#pragma unroll
    for (int mt = 0; mt < 2; ++mt) {
#pragma unroll
        for (int nt = 0; nt < 4; ++nt) o[mt][nt] = zero4;
#pragma unroll
        for (int r = 0; r < 4; ++r) { mr[mt][r] = -1e30f; lr[mt][r] = 0.f; }
    }

    ushort_t* const pw = &Ps[wave][0];

    for (int kt = 0; kt < 16; ++kt) {
        const int k0 = kt * 128;
        // ---- stage K tile [128 keys][64 d] ----
#pragma unroll
        for (int i = 0; i < 4; ++i) {
            const int c = tid + i * 256;            // 1024 8-elem chunks
            const int r = c >> 3, cc = (c & 7) * 8;
            *(uint4*)(&Ks[r * KP + cc]) =
                *(const uint4*)(&K[(rowb + k0 + r) * DMODEL + coff + cc]);
        }
        // ---- stage V tile transposed: VTs[d][key], pair-of-rows scheme ----
#pragma unroll
        for (int i = 0; i < 2; ++i) {
            const int c = tid + i * 256;            // 512 chunks
            const int k2 = c >> 3;                  // key pair 0..63
            const int cc = (c & 7) * 8;             // d chunk
            union { uint4 v; ushort_t u[8]; } a, bb;
            a.v  = *(const uint4*)(&V[(rowb + k0 + 2 * k2)     * DMODEL + coff + cc]);
            bb.v = *(const uint4*)(&V[(rowb + k0 + 2 * k2 + 1) * DMODEL + coff + cc]);
#pragma unroll
            for (int j = 0; j < 8; ++j) {
                const unsigned int pk = (unsigned int)a.u[j] | ((unsigned int)bb.u[j] << 16);
                *(unsigned int*)(&VTs[(cc + j) * VP + 2 * k2]) = pk;
            }
        }
        __syncthreads();

        // ---- S = Q' K^T (pre-scaled; C-layout: q=lq*4+r, key=lrow) ----
        f32x4 s[2][8];
#pragma unroll
        for (int mt = 0; mt < 2; ++mt)
#pragma unroll
            for (int nt = 0; nt < 8; ++nt) s[mt][nt] = zero4;
#pragma unroll
        for (int nt = 0; nt < 8; ++nt) {
#pragma unroll
            for (int ks = 0; ks < 2; ++ks) {
                const bf16x8 kf = *(const bf16x8*)(&Ks[(nt * 16 + lrow) * KP + ks * 32 + lq * 8]);
                s[0][nt] = __builtin_amdgcn_mfma_f32_16x16x32_bf16(qf[0][ks], kf, s[0][nt], 0, 0, 0);
                s[1][nt] = __builtin_amdgcn_mfma_f32_16x16x32_bf16(qf[1][ks], kf, s[1][nt], 0, 0, 0);
            }
        }

        // ---- mask ----
        if (!flags[qt * 16 + kt]) {
            for (int mt = 0; mt < 2; ++mt)
                for (int nt = 0; nt < 8; ++nt)
                    for (int r = 0; r < 4; ++r) {
                        const int qi = qw + mt * 16 + lq * 4 + r;
                        const int ki = k0 + nt * 16 + lrow;
                        if (mask[(size_t)qi * S_LEN + ki] == 0) s[mt][nt][r] = -1e9f;
                    }
        }

        // ---- online softmax (row = 16 consecutive lanes, fixed lq) ----
#pragma unroll
        for (int mt = 0; mt < 2; ++mt) {
#pragma unroll
            for (int r = 0; r < 4; ++r) {
                float v = s[mt][0][r];
#pragma unroll
                for (int nt = 1; nt < 8; ++nt) v = fmaxf(v, s[mt][nt][r]);
#pragma unroll
                for (int off = 1; off < 16; off <<= 1) v = fmaxf(v, __shfl_xor(v, off, 64));
                const float mn = fmaxf(mr[mt][r], v);
                const float alpha = __expf(mr[mt][r] - mn);
                mr[mt][r] = mn;
                float rs = 0.f;
#pragma unroll
                for (int nt = 0; nt < 8; ++nt) {
                    const float p = __expf(s[mt][nt][r] - mn);
                    s[mt][nt][r] = p;
                    rs += p;
                }
#pragma unroll
                for (int off = 1; off < 16; off <<= 1) rs += __shfl_xor(rs, off, 64);
                lr[mt][r] = lr[mt][r] * alpha + rs;
#pragma unroll
                for (int nt = 0; nt < 4; ++nt) o[mt][nt][r] *= alpha;
            }
        }

        // ---- O += P V in two 64-key halves via per-wave LDS relayout ----
#pragma unroll
        for (int half = 0; half < 2; ++half) {
            // write P (C-layout) into pw[q][k_local]
#pragma unroll
            for (int mt = 0; mt < 2; ++mt)
#pragma unroll
                for (int nt = 0; nt < 4; ++nt)
#pragma unroll
                    for (int r = 0; r < 4; ++r)
                        pw[(mt * 16 + lq * 4 + r) * PP + nt * 16 + lrow] =
                            f2bf(s[mt][half * 4 + nt][r]);
            // read A-layout fragments and multiply against V^T
#pragma unroll
            for (int ks = 0; ks < 2; ++ks) {
                const bf16x8 pf0 = *(const bf16x8*)(&pw[lrow * PP + ks * 32 + lq * 8]);
                const bf16x8 pf1 = *(const bf16x8*)(&pw[(16 + lrow) * PP + ks * 32 + lq * 8]);
                const int kb = half * 64 + ks * 32;       // key offset in tile
#pragma unroll
                for (int nt = 0; nt < 4; ++nt) {
                    const bf16x8 vf = *(const bf16x8*)(
                        &VTs[(nt * 16 + lrow) * VP + kb + lq * 8]);
                    o[0][nt] = __builtin_amdgcn_mfma_f32_16x16x32_bf16(pf0, vf, o[0][nt], 0, 0, 0);
                    o[1][nt] = __builtin_amdgcn_mfma_f32_16x16x32_bf16(pf1, vf, o[1][nt], 0, 0, 0);
                }
            }
        }
        __syncthreads();
    }

    // ---- epilogue: X row-major, head columns ----
#pragma unroll
    for (int mt = 0; mt < 2; ++mt) {
#pragma unroll
        for (int r = 0; r < 4; ++r) {
            const float inv = 1.f / lr[mt][r];
            const int si = qw + mt * 16 + lq * 4 + r;
#pragma unroll
            for (int nt = 0; nt < 4; ++nt) {
                const int dk = nt * 16 + lrow;
                X[(rowb + si) * DMODEL + coff + dk] = f2bf(o[mt][nt][r] * inv);
            }
        }
    }
}

// ---------------------------------------------------------------------------
// Buffer choreography (unchanged):
//   ws:    [W0 16MiB][W1 16MiB][W2 16MiB][dflag 8B][flags 1KB]
//   d_out: 32 MiB scratch until final GEMM.
//   1. detect (1 dispatch), mask_flags
//   2. conv_qkvw z=5: w_q,w_k,w_v -> W2[0:6MiB); query -> AcQ; key -> AcK
//   3. gemm256_qk (z=2): Q' (x0.125) -> W0, K -> W1
//   4. conv value -> AcV = d_out[0:16M)   (AcQ dead)
//   5. gemm_n64: V -> d_out[16:32M)       (AcK dead; Wv_c still live)
//   6. attn(Q=W0, K=W1, V=d_out+16M) -> X = W2   (weights dead)
//   7. conv w_o -> Wo_c = W1[0:2M)        (K dead)
//   8. gemm_n64: X(W2) @ Wo_c(W1) -> d_out f32 (AcV,V dead)
// ---------------------------------------------------------------------------
extern "C" void kernel_launch(void* const* d_in, const int* in_sizes, int n_in,
                              void* d_out, int out_size, void* d_ws, size_t ws_size,
                              hipStream_t stream)
{
    const void* query = d_in[0];
    const void* key   = d_in[1];
    const void* value = d_in[2];
    const int*  mask  = (const int*)d_in[3];
    const void* w_q = d_in[4];
    const void* b_q = d_in[5];
    const void* w_k = d_in[6];
    const void* b_k = d_in[7];
    const void* w_v = d_in[8];
    const void* b_v = d_in[9];
    const void* w_o = d_in[10];
    const void* b_o = d_in[11];

    const size_t TEN = (size_t)MROWS * DMODEL;   // 8M elements (16 MiB bf16)
    const size_t WEL = (size_t)DMODEL * DMODEL;  // 1M elements (2 MiB bf16)
    ushort_t* W0 = (ushort_t*)d_ws;
    ushort_t* W1 = W0 + TEN;
    ushort_t* W2 = W1 + TEN;
    int* dflag   = (int*)(W2 + TEN);             // [0]=act f32, [1]=weights f32
    int* flags   = dflag + 2;                    // 256 tile flags

    ushort_t* AcQ = (ushort_t*)d_out;            // d_out low half
    ushort_t* AcK = AcQ + TEN;                   // d_out high half
    ushort_t* AcV = AcQ;                         // reuses low half
    ushort_t* Vp  = AcK;                         // V output, d_out high half

    ushort_t* Wq_c = W2;
    ushort_t* Wk_c = W2 + WEL;
    ushort_t* Wv_c = W2 + 2 * WEL;
    ushort_t* Wo_c = W1;                         // after attn

    const int WN8 = (int)(WEL / 8);              // 131072
    const int AN8 = (int)(TEN / 8);              // 1048576

    detect_dtype2<<<2, 64, 0, stream>>>((const unsigned int*)query,
                                        (const unsigned int*)w_q, dflag);
    mask_flags<<<256, 256, 0, stream>>>(mask, flags);

    conv_qkvw<<<dim3(2048, 1, 5), 256, 0, stream>>>(
        w_q, Wq_c, w_k, Wk_c, w_v, Wv_c,
        query, AcQ, key, AcK, WN8, AN8, dflag);

    gemm256_qk<<<dim3(32, 4, 2), 512, 0, stream>>>(AcQ, Wq_c, b_q, W0,
                                                   AcK, Wk_c, b_k, W1, dflag);

    conv_bf16<<<2048, 256, 0, stream>>>(value, AcV, AN8, dflag, 0);
    gemm_n64<<<dim3(64, 16), 256, 0, stream>>>(AcV, Wv_c, b_v, Vp, dflag, 0);

    attn_mfma<<<dim3(64, 16), 256, 0, stream>>>(W0, W1, Vp, mask, flags, W2);

    conv_bf16<<<512, 256, 0, stream>>>(w_o, Wo_c, WN8, dflag, 1);
    gemm_n64<<<dim3(64, 16), 256, 0, stream>>>(W2, Wo_c, b_o, d_out, dflag, 1);
}

// Round 12
// 478.036 us; speedup vs baseline: 1.0263x; 1.0263x over previous
//
#include <hip/hip_runtime.h>
#include <stdint.h>

#define S_LEN 2048
#define NHEAD 16
#define DHEAD 64
#define DMODEL 1024
#define MROWS 8192  // B*S

typedef unsigned short ushort_t;
typedef __attribute__((ext_vector_type(8))) __bf16 bf16x8;
typedef __attribute__((ext_vector_type(4))) float f32x4;

__device__ __forceinline__ float bf2f(ushort_t h) {
    union { unsigned int u; float f; } v; v.u = ((unsigned int)h) << 16; return v.f;
}
__device__ __forceinline__ ushort_t f2bf(float f) {
    union { float f; unsigned int u; } v; v.f = f;
    unsigned int u = v.u + 0x7fffu + ((v.u >> 16) & 1u);  // round-to-nearest-even
    return (ushort_t)(u >> 16);
}

// Direct global->LDS 16B async copy. LDS dest is wave-uniform base + lane*16.
__device__ __forceinline__ void gload_lds16(const void* g, void* l)
{
    auto* g1 = reinterpret_cast<const __attribute__((address_space(1))) void*>(
        reinterpret_cast<uintptr_t>(g));
    auto* l3 = reinterpret_cast<__attribute__((address_space(3))) void*>(
        reinterpret_cast<uintptr_t>(l));
    __builtin_amdgcn_global_load_lds(g1, l3, 16, 0, 0);
}

// ---------------------------------------------------------------------------
// Dtype detection, both tensors in one dispatch.
// ---------------------------------------------------------------------------
__global__ void detect_dtype2(const unsigned int* __restrict__ q,
                              const unsigned int* __restrict__ w,
                              int* __restrict__ flag)
{
    __shared__ int cnt;
    if (threadIdx.x == 0) cnt = 0;
    __syncthreads();
    const unsigned int* src = blockIdx.x ? w : q;
    int c = 0;
    for (int i = 0; i < 8; ++i) {
        const unsigned int word = src[threadIdx.x * 8 + i];   // first 512 words
        const unsigned int lo = word & 0xffffu;
        const unsigned int e = (lo >> 7) & 0xffu;        // bf16 exponent field
        if (lo == 0u || (e >= 96u && e <= 160u)) ++c;    // "sane" bf16
    }
    atomicAdd(&cnt, c);
    __syncthreads();
    if (threadIdx.x == 0) flag[blockIdx.x] = (cnt < 400) ? 1 : 0;
}

// ---------------------------------------------------------------------------
// mask -> per 128x128 tile flag (1 = all nonzero -> skip elementwise path)
// ---------------------------------------------------------------------------
__global__ void mask_flags(const int* __restrict__ mask, int* __restrict__ flags)
{
    __shared__ int ok_s;
    if (threadIdx.x == 0) ok_s = 1;
    __syncthreads();
    const int t = blockIdx.x;            // 0..255
    const int tq = t >> 4, tk = t & 15;
    int ok = 1;
    for (int i = 0; i < 64; ++i) {
        const int idx = i * 256 + threadIdx.x;    // 0..16383
        const int r = idx >> 7, c = idx & 127;
        if (mask[(size_t)(tq * 128 + r) * S_LEN + tk * 128 + c] == 0) { ok = 0; break; }
    }
    if (!ok) atomicAnd(&ok_s, 0);
    __syncthreads();
    if (threadIdx.x == 0) flags[t] = ok_s;
}

__device__ __forceinline__ float loadscal(const void* b, int i, bool f32)
{
    return f32 ? ((const float*)b)[i] : bf2f(((const ushort_t*)b)[i]);
}

// ---------------------------------------------------------------------------
// One-shot dtype normalization: src (f32 or bf16, per flag) -> bf16.
// ---------------------------------------------------------------------------
__device__ __forceinline__ void conv_body(const void* __restrict__ src,
                                          ushort_t* __restrict__ dst,
                                          int n8, bool f32)
{
    const int stride = gridDim.x * 256;
    for (int i = blockIdx.x * 256 + threadIdx.x; i < n8; i += stride) {
        if (f32) {
            const float4 a = ((const float4*)src)[2 * (size_t)i];
            const float4 b = ((const float4*)src)[2 * (size_t)i + 1];
            union { ushort_t u[8]; uint4 v; } p;
            p.u[0] = f2bf(a.x); p.u[1] = f2bf(a.y); p.u[2] = f2bf(a.z); p.u[3] = f2bf(a.w);
            p.u[4] = f2bf(b.x); p.u[5] = f2bf(b.y); p.u[6] = f2bf(b.z); p.u[7] = f2bf(b.w);
            ((uint4*)dst)[i] = p.v;
        } else {
            ((uint4*)dst)[i] = ((const uint4*)src)[i];
        }
    }
}

__global__ __launch_bounds__(256)
void conv_bf16(const void* __restrict__ src, ushort_t* __restrict__ dst,
               int n8, const int* __restrict__ dflag, int fidx)
{
    conv_body(src, dst, n8, dflag[fidx] != 0);
}

// Five-slice upfront conversion: z=0..2 weights (dflag[1]), z=3..4
// activations (dflag[0]).
__global__ __launch_bounds__(256)
void conv_qkvw(const void* __restrict__ wq, ushort_t* __restrict__ dwq,
               const void* __restrict__ wk, ushort_t* __restrict__ dwk,
               const void* __restrict__ wv, ushort_t* __restrict__ dwv,
               const void* __restrict__ aq, ushort_t* __restrict__ daq,
               const void* __restrict__ ak, ushort_t* __restrict__ dak,
               int wn8, int an8, const int* __restrict__ dflag)
{
    const int z = blockIdx.z;
    const void* src;
    ushort_t* dst;
    int n8;
    bool f32;
    if (z < 3) {
        n8 = wn8; f32 = dflag[1] != 0;
        src = (z == 0) ? wq : (z == 1) ? wk : wv;
        dst = (z == 0) ? dwq : (z == 1) ? dwk : dwv;
    } else {
        n8 = an8; f32 = dflag[0] != 0;
        src = (z == 3) ? aq : ak;
        dst = (z == 3) ? daq : dak;
    }
    conv_body(src, dst, n8, f32);
}

// ---------------------------------------------------------------------------
// 128x128-tile bf16 GEMM core (proven best for V/O at this shape; six
// structural variants all landed within noise of this config): BK=32,
// 3-buffer pipeline, COUNTED vmcnt across raw s_barrier.
// ---------------------------------------------------------------------------
__device__ __forceinline__ void gemm_core(
    const ushort_t* __restrict__ A, const ushort_t* __restrict__ W,
    const void* __restrict__ bias, void* __restrict__ out,
    bool bf32, bool outf, float scale,
    ushort_t (&As)[3][128 * 32], ushort_t (&Bs)[3][128 * 32])
{
    constexpr int K = DMODEL, N = DMODEL;
    const int tid = threadIdx.x;
    const int lane = tid & 63;
    const int wave = tid >> 6;
    const int lrow = lane & 15, lq = lane >> 4;
    const int m0 = blockIdx.x * 128;
    const int n0 = blockIdx.y * 128;
    const int wr = (wave >> 1) * 64;
    const int wc = (wave & 1) * 64;

    const f32x4 zero4 = {0.f, 0.f, 0.f, 0.f};
    f32x4 acc[4][4];
#pragma unroll
    for (int i = 0; i < 4; ++i)
#pragma unroll
        for (int j = 0; j < 4; ++j) acc[i][j] = zero4;

    const int r0  = tid >> 2;
    const int cc0 = (tid & 3) * 8;
    const int lb  = wave * 64 * 8;
    const int lb1 = (wave * 64 + 256) * 8;

    auto stage = [&](int buf, int k0) __attribute__((always_inline)) {
        gload_lds16(&A[(size_t)(m0 + r0) * K + k0 + cc0],      &As[buf][lb]);
        gload_lds16(&A[(size_t)(m0 + r0 + 64) * K + k0 + cc0], &As[buf][lb1]);
        gload_lds16(&W[(size_t)(n0 + r0) * K + k0 + cc0],      &Bs[buf][lb]);
        gload_lds16(&W[(size_t)(n0 + r0 + 64) * K + k0 + cc0], &Bs[buf][lb1]);
    };
    auto compute = [&](int buf) __attribute__((always_inline)) {
        bf16x8 af[4], bfr[4];
#pragma unroll
        for (int t = 0; t < 4; ++t) {
            af[t]  = *(const bf16x8*)(&As[buf][(wr + t * 16 + lrow) * 32 + lq * 8]);
            bfr[t] = *(const bf16x8*)(&Bs[buf][(wc + t * 16 + lrow) * 32 + lq * 8]);
        }
        __builtin_amdgcn_s_setprio(1);
#pragma unroll
        for (int mt = 0; mt < 4; ++mt)
#pragma unroll
            for (int nt = 0; nt < 4; ++nt)
                acc[mt][nt] = __builtin_amdgcn_mfma_f32_16x16x32_bf16(
                    af[mt], bfr[nt], acc[mt][nt], 0, 0, 0);
        __builtin_amdgcn_s_setprio(0);
    };

    stage(0, 0);
    stage(1, 32);
    asm volatile("s_waitcnt vmcnt(4)" ::: "memory");
    __builtin_amdgcn_s_barrier();

#pragma unroll 1
    for (int tt = 0; tt < 32; ++tt) {
        if (tt < 30) stage((tt + 2) % 3, (tt + 2) * 32);
        compute(tt % 3);
        if (tt < 31) {
            if (tt < 30) asm volatile("s_waitcnt vmcnt(4)" ::: "memory");
            else         asm volatile("s_waitcnt vmcnt(0)" ::: "memory");
            __builtin_amdgcn_s_barrier();
        }
    }

#pragma unroll
    for (int nt = 0; nt < 4; ++nt) {
        const int n = n0 + wc + nt * 16 + lrow;
        const float bv = loadscal(bias, n, bf32);
#pragma unroll
        for (int mt = 0; mt < 4; ++mt) {
            const int mbase = m0 + wr + mt * 16 + lq * 4;
#pragma unroll
            for (int r = 0; r < 4; ++r) {
                const float v = (acc[mt][nt][r] + bv) * scale;
                const size_t o = (size_t)(mbase + r) * N + n;
                if (outf) ((float*)out)[o] = v;
                else      ((ushort_t*)out)[o] = f2bf(v);
            }
        }
    }
}

// Single 128^2 GEMM for V/O: grid (64,8)=512 blocks -> full chip, 2-3/CU.
__global__ __launch_bounds__(256, 3)
void gemm_bf16(const ushort_t* __restrict__ A, const ushort_t* __restrict__ W,
               const void* __restrict__ bias, void* __restrict__ out,
               const int* __restrict__ dflag, int outf)
{
    __shared__ ushort_t As[3][128 * 32];
    __shared__ ushort_t Bs[3][128 * 32];
    gemm_core(A, W, bias, out, dflag[1] != 0, outf != 0, 1.0f, As, Bs);
}

// ---------------------------------------------------------------------------
// 256x256-tile bf16 GEMM (QK; 3-buffer counted-vmcnt, verified rounds 9/10).
// Grid (32,4,2) = 256 blocks = 1 block/CU.
// ---------------------------------------------------------------------------
__device__ __forceinline__ void gemm256_core(
    const ushort_t* __restrict__ A, const ushort_t* __restrict__ W,
    const void* __restrict__ bias, void* __restrict__ out,
    bool bf32, bool outf, float scale,
    ushort_t (&As)[3][256 * 32], ushort_t (&Bs)[3][256 * 32])
{
    constexpr int K = DMODEL, N = DMODEL;
    const int tid = threadIdx.x;             // 0..511
    const int lane = tid & 63;
    const int wave = tid >> 6;               // 0..7
    const int lrow = lane & 15, lq = lane >> 4;
    const int Rw = (wave >> 2) * 128;        // wave row base (2 M-waves)
    const int Cw = (wave & 3) * 64;          // wave col base (4 N-waves)
    const int m0 = blockIdx.x * 256;
    const int n0 = blockIdx.y * 256;

    const f32x4 zero4 = {0.f, 0.f, 0.f, 0.f};
    f32x4 acc[8][4];
#pragma unroll
    for (int i = 0; i < 8; ++i)
#pragma unroll
        for (int j = 0; j < 4; ++j) acc[i][j] = zero4;

    const int rowA = tid >> 2;                         // 0..127
    const int sl   = (((tid & 3) ^ (rowA & 3))) * 8;   // swizzled elem offset
    const int lb0  = (wave * 64) * 8;                  // wave-uniform LDS dest
    const int lb1  = (512 + wave * 64) * 8;

    auto stage = [&](int buf, int k0) __attribute__((always_inline)) {
        gload_lds16(&A[(size_t)(m0 + rowA) * K + k0 + sl],       &As[buf][lb0]);
        gload_lds16(&A[(size_t)(m0 + rowA + 128) * K + k0 + sl], &As[buf][lb1]);
        gload_lds16(&W[(size_t)(n0 + rowA) * K + k0 + sl],       &Bs[buf][lb0]);
        gload_lds16(&W[(size_t)(n0 + rowA + 128) * K + k0 + sl], &Bs[buf][lb1]);
    };

    const int lqs8 = (lq ^ (lrow & 3)) * 8;

    auto compute = [&](int buf) __attribute__((always_inline)) {
        const ushort_t* Ad = As[buf];
        const ushort_t* Bd = Bs[buf];
        bf16x8 bfr[4], af[4];
#pragma unroll
        for (int ni = 0; ni < 4; ++ni)
            bfr[ni] = *(const bf16x8*)(&Bd[(Cw + ni * 16 + lrow) * 32 + lqs8]);
#pragma unroll
        for (int mi = 0; mi < 4; ++mi)
            af[mi] = *(const bf16x8*)(&Ad[(Rw + mi * 16 + lrow) * 32 + lqs8]);
        __builtin_amdgcn_s_setprio(1);
#pragma unroll
        for (int mi = 0; mi < 4; ++mi)
#pragma unroll
            for (int ni = 0; ni < 4; ++ni)
                acc[mi][ni] = __builtin_amdgcn_mfma_f32_16x16x32_bf16(
                    af[mi], bfr[ni], acc[mi][ni], 0, 0, 0);
        __builtin_amdgcn_s_setprio(0);
#pragma unroll
        for (int mi = 0; mi < 4; ++mi)
            af[mi] = *(const bf16x8*)(&Ad[(Rw + 64 + mi * 16 + lrow) * 32 + lqs8]);
        __builtin_amdgcn_s_setprio(1);
#pragma unroll
        for (int mi = 0; mi < 4; ++mi)
#pragma unroll
            for (int ni = 0; ni < 4; ++ni)
                acc[4 + mi][ni] = __builtin_amdgcn_mfma_f32_16x16x32_bf16(
                    af[mi], bfr[ni], acc[4 + mi][ni], 0, 0, 0);
        __builtin_amdgcn_s_setprio(0);
    };

    stage(0, 0);
    stage(1, 32);
    asm volatile("s_waitcnt vmcnt(4)" ::: "memory");
    __builtin_amdgcn_s_barrier();

#pragma unroll 1
    for (int tt = 0; tt < 32; ++tt) {
        if (tt < 30) stage((tt + 2) % 3, (tt + 2) * 32);
        compute(tt % 3);
        if (tt < 31) {
            if (tt < 30) asm volatile("s_waitcnt vmcnt(4)" ::: "memory");
            else         asm volatile("s_waitcnt vmcnt(0)" ::: "memory");
            __builtin_amdgcn_s_barrier();
        }
    }

#pragma unroll
    for (int ni = 0; ni < 4; ++ni) {
        const int n = n0 + Cw + ni * 16 + lrow;
        const float bv = loadscal(bias, n, bf32);
#pragma unroll
        for (int mi = 0; mi < 8; ++mi) {
            const int mbase = m0 + Rw + (mi >> 2) * 64 + (mi & 3) * 16 + lq * 4;
#pragma unroll
            for (int r = 0; r < 4; ++r) {
                const float v = (acc[mi][ni][r] + bv) * scale;
                const size_t o = (size_t)(mbase + r) * N + n;
                if (outf) ((float*)out)[o] = v;
                else      ((ushort_t*)out)[o] = f2bf(v);
            }
        }
    }
}

// Batched Q/K projection: z=0 -> Q with epilogue scale 0.125 (folds the
// attention 1/sqrt(64) into Q'); z=1 -> K.
__global__ __launch_bounds__(512, 2)
void gemm256_qk(const ushort_t* __restrict__ A0, const ushort_t* __restrict__ W0,
                const void* __restrict__ b0, void* __restrict__ o0,
                const ushort_t* __restrict__ A1, const ushort_t* __restrict__ W1,
                const void* __restrict__ b1, void* __restrict__ o1,
                const int* __restrict__ dflag)
{
    __shared__ ushort_t As[3][256 * 32];   // 48 KB
    __shared__ ushort_t Bs[3][256 * 32];   // 48 KB
    const bool z = blockIdx.z != 0;
    gemm256_core(z ? A1 : A0, z ? W1 : W0, z ? b1 : b0, z ? o1 : o0,
                 dflag[1] != 0, false, z ? 1.0f : 0.125f, As, Bs);
}

// ---------------------------------------------------------------------------
// MFMA flash attention — FROZEN inner kernel; grid (x=bh, y=q0t) for XCD L2
// locality (verified: FETCH 139MB -> 39MB, dur 197 -> 192).
// Q arrives pre-scaled by 0.125 from the Q projection.
// ---------------------------------------------------------------------------
__global__ __launch_bounds__(256, 2)
void attn_mfma(const ushort_t* __restrict__ Q, const ushort_t* __restrict__ K,
               const ushort_t* __restrict__ V, const int* __restrict__ mask,
               const int* __restrict__ flags, ushort_t* __restrict__ X)
{
    constexpr int KP = 72;    // K tile row stride
    constexpr int VP = 130;   // V^T tile row stride (even; bank-spread)
    constexpr int PP = 72;    // P tile row stride
    __shared__ ushort_t Ks[128 * KP];       // 18.0 KB
    __shared__ ushort_t VTs[64 * VP];       // 16.3 KB
    __shared__ ushort_t Ps[4][32 * PP];     // 18.0 KB (per-wave)

    const int tid = threadIdx.x;
    const int lane = tid & 63;
    const int wave = tid >> 6;
    const int lrow = lane & 15, lq = lane >> 4;
    const int bh = blockIdx.x, b = bh >> 4, h = bh & 15;
    const int qt = blockIdx.y;
    const int q0 = qt * 128;
    const int qw = q0 + wave * 32;
    const int coff = h * 64;
    const size_t rowb = (size_t)b * S_LEN;

    // Q fragments (A-operand: m=lrow, k-chunk=lq*8) live in registers
    bf16x8 qf[2][2];
#pragma unroll
    for (int mt = 0; mt < 2; ++mt)
#pragma unroll
        for (int ks = 0; ks < 2; ++ks)
            qf[mt][ks] = *(const bf16x8*)(
                &Q[(rowb + qw + mt * 16 + lrow) * DMODEL + coff + ks * 32 + lq * 8]);

    const f32x4 zero4 = {0.f, 0.f, 0.f, 0.f};
    f32x4 o[2][4];
    float mr[2][4], lr[2][4];
#pragma unroll
    for (int mt = 0; mt < 2; ++mt) {
#pragma unroll
        for (int nt = 0; nt < 4; ++nt) o[mt][nt] = zero4;
#pragma unroll
        for (int r = 0; r < 4; ++r) { mr[mt][r] = -1e30f; lr[mt][r] = 0.f; }
    }

    ushort_t* const pw = &Ps[wave][0];

    for (int kt = 0; kt < 16; ++kt) {
        const int k0 = kt * 128;
        // ---- stage K tile [128 keys][64 d] ----
#pragma unroll
        for (int i = 0; i < 4; ++i) {
            const int c = tid + i * 256;            // 1024 8-elem chunks
            const int r = c >> 3, cc = (c & 7) * 8;
            *(uint4*)(&Ks[r * KP + cc]) =
                *(const uint4*)(&K[(rowb + k0 + r) * DMODEL + coff + cc]);
        }
        // ---- stage V tile transposed: VTs[d][key], pair-of-rows scheme ----
#pragma unroll
        for (int i = 0; i < 2; ++i) {
            const int c = tid + i * 256;            // 512 chunks
            const int k2 = c >> 3;                  // key pair 0..63
            const int cc = (c & 7) * 8;             // d chunk
            union { uint4 v; ushort_t u[8]; } a, bb;
            a.v  = *(const uint4*)(&V[(rowb + k0 + 2 * k2)     * DMODEL + coff + cc]);
            bb.v = *(const uint4*)(&V[(rowb + k0 + 2 * k2 + 1) * DMODEL + coff + cc]);
#pragma unroll
            for (int j = 0; j < 8; ++j) {
                const unsigned int pk = (unsigned int)a.u[j] | ((unsigned int)bb.u[j] << 16);
                *(unsigned int*)(&VTs[(cc + j) * VP + 2 * k2]) = pk;
            }
        }
        __syncthreads();

        // ---- S = Q' K^T (pre-scaled; C-layout: q=lq*4+r, key=lrow) ----
        f32x4 s[2][8];
#pragma unroll
        for (int mt = 0; mt < 2; ++mt)
#pragma unroll
            for (int nt = 0; nt < 8; ++nt) s[mt][nt] = zero4;
#pragma unroll
        for (int nt = 0; nt < 8; ++nt) {
#pragma unroll
            for (int ks = 0; ks < 2; ++ks) {
                const bf16x8 kf = *(const bf16x8*)(&Ks[(nt * 16 + lrow) * KP + ks * 32 + lq * 8]);
                s[0][nt] = __builtin_amdgcn_mfma_f32_16x16x32_bf16(qf[0][ks], kf, s[0][nt], 0, 0, 0);
                s[1][nt] = __builtin_amdgcn_mfma_f32_16x16x32_bf16(qf[1][ks], kf, s[1][nt], 0, 0, 0);
            }
        }

        // ---- mask ----
        if (!flags[qt * 16 + kt]) {
            for (int mt = 0; mt < 2; ++mt)
                for (int nt = 0; nt < 8; ++nt)
                    for (int r = 0; r < 4; ++r) {
                        const int qi = qw + mt * 16 + lq * 4 + r;
                        const int ki = k0 + nt * 16 + lrow;
                        if (mask[(size_t)qi * S_LEN + ki] == 0) s[mt][nt][r] = -1e9f;
                    }
        }

        // ---- online softmax (row = 16 consecutive lanes, fixed lq) ----
#pragma unroll
        for (int mt = 0; mt < 2; ++mt) {
#pragma unroll
            for (int r = 0; r < 4; ++r) {
                float v = s[mt][0][r];
#pragma unroll
                for (int nt = 1; nt < 8; ++nt) v = fmaxf(v, s[mt][nt][r]);
#pragma unroll
                for (int off = 1; off < 16; off <<= 1) v = fmaxf(v, __shfl_xor(v, off, 64));
                const float mn = fmaxf(mr[mt][r], v);
                const float alpha = __expf(mr[mt][r] - mn);
                mr[mt][r] = mn;
                float rs = 0.f;
#pragma unroll
                for (int nt = 0; nt < 8; ++nt) {
                    const float p = __expf(s[mt][nt][r] - mn);
                    s[mt][nt][r] = p;
                    rs += p;
                }
#pragma unroll
                for (int off = 1; off < 16; off <<= 1) rs += __shfl_xor(rs, off, 64);
                lr[mt][r] = lr[mt][r] * alpha + rs;
#pragma unroll
                for (int nt = 0; nt < 4; ++nt) o[mt][nt][r] *= alpha;
            }
        }

        // ---- O += P V in two 64-key halves via per-wave LDS relayout ----
#pragma unroll
        for (int half = 0; half < 2; ++half) {
            // write P (C-layout) into pw[q][k_local]
#pragma unroll
            for (int mt = 0; mt < 2; ++mt)
#pragma unroll
                for (int nt = 0; nt < 4; ++nt)
#pragma unroll
                    for (int r = 0; r < 4; ++r)
                        pw[(mt * 16 + lq * 4 + r) * PP + nt * 16 + lrow] =
                            f2bf(s[mt][half * 4 + nt][r]);
            // read A-layout fragments and multiply against V^T
#pragma unroll
            for (int ks = 0; ks < 2; ++ks) {
                const bf16x8 pf0 = *(const bf16x8*)(&pw[lrow * PP + ks * 32 + lq * 8]);
                const bf16x8 pf1 = *(const bf16x8*)(&pw[(16 + lrow) * PP + ks * 32 + lq * 8]);
                const int kb = half * 64 + ks * 32;       // key offset in tile
#pragma unroll
                for (int nt = 0; nt < 4; ++nt) {
                    const bf16x8 vf = *(const bf16x8*)(
                        &VTs[(nt * 16 + lrow) * VP + kb + lq * 8]);
                    o[0][nt] = __builtin_amdgcn_mfma_f32_16x16x32_bf16(pf0, vf, o[0][nt], 0, 0, 0);
                    o[1][nt] = __builtin_amdgcn_mfma_f32_16x16x32_bf16(pf1, vf, o[1][nt], 0, 0, 0);
                }
            }
        }
        __syncthreads();
    }

    // ---- epilogue: X row-major, head columns ----
#pragma unroll
    for (int mt = 0; mt < 2; ++mt) {
#pragma unroll
        for (int r = 0; r < 4; ++r) {
            const float inv = 1.f / lr[mt][r];
            const int si = qw + mt * 16 + lq * 4 + r;
#pragma unroll
            for (int nt = 0; nt < 4; ++nt) {
                const int dk = nt * 16 + lrow;
                X[(rowb + si) * DMODEL + coff + dk] = f2bf(o[mt][nt][r] * inv);
            }
        }
    }
}

// ---------------------------------------------------------------------------
// Buffer choreography (round-10 best configuration, 481.9 us):
//   ws:    [W0 16MiB][W1 16MiB][W2 16MiB][dflag 8B][flags 1KB]
//   d_out: 32 MiB scratch until final GEMM.
//   1. detect (1 dispatch), mask_flags
//   2. conv_qkvw z=5: w_q,w_k,w_v -> W2[0:6MiB); query -> AcQ; key -> AcK
//   3. gemm256_qk (z=2): Q' (x0.125) -> W0, K -> W1
//   4. conv value -> AcV = d_out[0:16M)   (AcQ dead)
//   5. gemm_bf16 (128^2): V -> d_out[16:32M)  (AcK dead; Wv_c still live)
//   6. attn(Q=W0, K=W1, V=d_out+16M) -> X = W2   (weights dead)
//   7. conv w_o -> Wo_c = W1[0:2M)        (K dead)
//   8. gemm_bf16 (128^2): X(W2) @ Wo_c(W1) -> d_out f32 (AcV,V dead)
// ---------------------------------------------------------------------------
extern "C" void kernel_launch(void* const* d_in, const int* in_sizes, int n_in,
                              void* d_out, int out_size, void* d_ws, size_t ws_size,
                              hipStream_t stream)
{
    const void* query = d_in[0];
    const void* key   = d_in[1];
    const void* value = d_in[2];
    const int*  mask  = (const int*)d_in[3];
    const void* w_q = d_in[4];
    const void* b_q = d_in[5];
    const void* w_k = d_in[6];
    const void* b_k = d_in[7];
    const void* w_v = d_in[8];
    const void* b_v = d_in[9];
    const void* w_o = d_in[10];
    const void* b_o = d_in[11];

    const size_t TEN = (size_t)MROWS * DMODEL;   // 8M elements (16 MiB bf16)
    const size_t WEL = (size_t)DMODEL * DMODEL;  // 1M elements (2 MiB bf16)
    ushort_t* W0 = (ushort_t*)d_ws;
    ushort_t* W1 = W0 + TEN;
    ushort_t* W2 = W1 + TEN;
    int* dflag   = (int*)(W2 + TEN);             // [0]=act f32, [1]=weights f32
    int* flags   = dflag + 2;                    // 256 tile flags

    ushort_t* AcQ = (ushort_t*)d_out;            // d_out low half
    ushort_t* AcK = AcQ + TEN;                   // d_out high half
    ushort_t* AcV = AcQ;                         // reuses low half
    ushort_t* Vp  = AcK;                         // V output, d_out high half

    ushort_t* Wq_c = W2;
    ushort_t* Wk_c = W2 + WEL;
    ushort_t* Wv_c = W2 + 2 * WEL;
    ushort_t* Wo_c = W1;                         // after attn

    const int WN8 = (int)(WEL / 8);              // 131072
    const int AN8 = (int)(TEN / 8);              // 1048576

    detect_dtype2<<<2, 64, 0, stream>>>((const unsigned int*)query,
                                        (const unsigned int*)w_q, dflag);
    mask_flags<<<256, 256, 0, stream>>>(mask, flags);

    conv_qkvw<<<dim3(2048, 1, 5), 256, 0, stream>>>(
        w_q, Wq_c, w_k, Wk_c, w_v, Wv_c,
        query, AcQ, key, AcK, WN8, AN8, dflag);

    gemm256_qk<<<dim3(32, 4, 2), 512, 0, stream>>>(AcQ, Wq_c, b_q, W0,
                                                   AcK, Wk_c, b_k, W1, dflag);

    conv_bf16<<<2048, 256, 0, stream>>>(value, AcV, AN8, dflag, 0);
    gemm_bf16<<<dim3(64, 8), 256, 0, stream>>>(AcV, Wv_c, b_v, Vp, dflag, 0);

    attn_mfma<<<dim3(64, 16), 256, 0, stream>>>(W0, W1, Vp, mask, flags, W2);

    conv_bf16<<<512, 256, 0, stream>>>(w_o, Wo_c, WN8, dflag, 1);
    gemm_bf16<<<dim3(64, 8), 256, 0, stream>>>(W2, Wo_c, b_o, d_out, dflag, 1);
}